// Round 2
// baseline (561.587 us; speedup 1.0000x reference)
//
#include <hip/hip_runtime.h>
#include <math.h>

#define IS2 0.70710678118654752440f

// d_ws layout (float elements):
//   K2  [512][8]        @ 0        (is2 * K512[i][m2], transposed, i contiguous)
//   K4  [256][8]        @ 4096     (0.5 * K256[i][m4], transposed)
//   Fc  [32][1024]      @ 6144     (dense column functionals)
//   T2  [64][32][1024]  @ 38912    (row-reduced per image)
//   G   [64][32][32]    @ 2136064
// total = 2201600 floats = 8,806,400 bytes

__device__ __forceinline__ float tri_f(float x) {
    float a = 1.0f - fabsf(x);
    return a > 0.0f ? a : 0.0f;
}

__global__ void init_weights(float* __restrict__ ws) {
    __shared__ float norm512[8];
    __shared__ float norm256[8];
    int t = threadIdx.x;
    if (t < 8) {
        float c = 64.0f * t + 31.5f;
        float s = 0.0f;
        for (int m = 0; m < 512; ++m) s += tri_f((m - c) * (1.0f / 64.0f));
        norm512[t] = s;
    } else if (t < 16) {
        int i = t - 8;
        float c = 32.0f * i + 15.5f;
        float s = 0.0f;
        for (int m = 0; m < 256; ++m) s += tri_f((m - c) * (1.0f / 32.0f));
        norm256[i] = s;
    }
    __syncthreads();

    float* K2 = ws;
    float* K4 = ws + 4096;
    float* Fc = ws + 6144;

    for (int idx = t; idx < 4096; idx += 256) {
        int m2 = idx >> 3, i = idx & 7;
        K2[idx] = IS2 * tri_f((m2 - (64.0f * i + 31.5f)) * (1.0f / 64.0f)) / norm512[i];
    }
    for (int idx = t; idx < 2048; idx += 256) {
        int m4 = idx >> 3, i = idx & 7;
        K4[idx] = 0.5f * tri_f((m4 - (32.0f * i + 15.5f)) * (1.0f / 32.0f)) / norm256[i];
    }
    for (int idx = t; idx < 32768; idx += 256) {
        int jp = idx >> 10, q = idx & 1023;
        int s = jp >> 3, i = jp & 7;
        float v;
        if (s == 0) {
            v = 0.5f * tri_f(((q >> 2) - (32.0f * i + 15.5f)) * (1.0f / 32.0f)) / norm256[i];
        } else if (s == 1) {
            float sg = ((q & 3) < 2) ? 1.0f : -1.0f;
            v = sg * 0.5f * tri_f(((q >> 2) - (32.0f * i + 15.5f)) * (1.0f / 32.0f)) / norm256[i];
        } else if (s == 2) {
            v = IS2 * tri_f(((q >> 1) - (64.0f * i + 31.5f)) * (1.0f / 64.0f)) / norm512[i];
        } else {
            float sg = ((q & 1) == 0) ? 1.0f : -1.0f;
            v = sg * IS2 * tri_f(((q >> 1) - (64.0f * i + 31.5f)) * (1.0f / 64.0f)) / norm512[i];
        }
        Fc[idx] = v;
    }
}

// k1: row-direction reduction. Grid (16 col-chunks, 64 images), block 256 = 4 waves.
// Wave w handles rows [w*256, (w+1)*256), column q = chunk*64 + lane.
__global__ __launch_bounds__(256) void k1_rowreduce(const float* __restrict__ x,
                                                    const float* __restrict__ ws,
                                                    float* __restrict__ T2) {
    const int b = blockIdx.y;
    const int chunk = blockIdx.x;
    const int t = threadIdx.x;
    const int w = t >> 6;
    const int l = t & 63;
    const int q = chunk * 64 + l;

    const float* K2 = ws;
    const float* K4 = ws + 4096;
    const float* xp = x + (size_t)b * 1048576 + (size_t)(w * 256) * 1024 + q;

    float acc0[8], acc1[8], acc2[8], acc3[8];
#pragma unroll
    for (int i = 0; i < 8; ++i) { acc0[i] = 0.f; acc1[i] = 0.f; acc2[i] = 0.f; acc3[i] = 0.f; }

    const int m2base = w * 128;
    const int m4base = w * 64;

    for (int g = 0; g < 64; ++g) {
        float x0 = xp[0];
        float x1 = xp[1024];
        float x2 = xp[2048];
        float x3 = xp[3072];
        xp += 4096;
        float a2a = x0 + x1, d2a = x0 - x1;
        float a2b = x2 + x3, d2b = x2 - x3;
        float s4 = a2a + a2b, r4 = a2a - a2b;
        const float* wa = K2 + (size_t)(m2base + 2 * g) * 8;
        const float* wb = wa + 8;
        const float* w4 = K4 + (size_t)(m4base + g) * 8;
#pragma unroll
        for (int i = 0; i < 8; ++i) {
            float wai = wa[i], wbi = wb[i], w4i = w4[i];
            acc2[i] += wai * a2a + wbi * a2b;
            acc3[i] += wai * d2a + wbi * d2b;
            acc0[i] += w4i * s4;
            acc1[i] += w4i * r4;
        }
    }

    __shared__ float red[4][32][64];
#pragma unroll
    for (int i = 0; i < 8; ++i) {
        red[w][i][l]      = acc0[i];
        red[w][8 + i][l]  = acc1[i];
        red[w][16 + i][l] = acc2[i];
        red[w][24 + i][l] = acc3[i];
    }
    __syncthreads();

    for (int idx = t; idx < 2048; idx += 256) {
        int jp = idx >> 6, c = idx & 63;
        float s = red[0][jp][c] + red[1][jp][c] + red[2][jp][c] + red[3][jp][c];
        T2[((size_t)b * 32 + jp) * 1024 + chunk * 64 + c] = s;
    }
}

// k2: G[b][j'][j''] = sum_q T2[b][j'][q] * Fc[j''][q].  Grid 64 blocks, 256 threads.
__global__ __launch_bounds__(256) void k2_colreduce(const float* __restrict__ T2,
                                                    const float* __restrict__ Fc,
                                                    float* __restrict__ G) {
    const int b = blockIdx.x;
    const int t = threadIdx.x;
    const int jpp = t & 31;
    const int jp0 = t >> 5;
    const float4* fcv = (const float4*)(Fc + (size_t)jpp * 1024);

#pragma unroll
    for (int rep = 0; rep < 4; ++rep) {
        int jp = rep * 8 + jp0;
        const float4* t2v = (const float4*)(T2 + ((size_t)b * 32 + jp) * 1024);
        float s = 0.0f;
#pragma unroll 4
        for (int qv = 0; qv < 256; ++qv) {
            float4 a = t2v[qv];
            float4 f = fcv[qv];
            s += a.x * f.x + a.y * f.y + a.z * f.z + a.w * f.w;
        }
        G[((size_t)b * 32 + jp) * 32 + jpp] = s;
    }
}

// k3: out[b, p, n] = bias[n] + sum_k feat_k * W[k][n]. Grid (64 positions, 64 images).
__global__ __launch_bounds__(256) void k3_project(const float* __restrict__ G,
                                                  const float* __restrict__ W,
                                                  const float* __restrict__ bias,
                                                  float* __restrict__ out) {
    const int b = blockIdx.y;
    const int p = blockIdx.x;
    const int n = threadIdx.x;
    const int i = p >> 3, j = p & 7;
    const float* g = G + (size_t)b * 1024;
    // maps: cA2(0,0) cH2(1,0) cV2(0,1) cD2(1,1) cH1(3,2) cV1(2,3) cD1(3,3)
    float f0 = g[(0 * 8 + i) * 32 + 0 * 8 + j];
    float f1 = g[(1 * 8 + i) * 32 + 0 * 8 + j];
    float f2 = g[(0 * 8 + i) * 32 + 1 * 8 + j];
    float f3 = g[(1 * 8 + i) * 32 + 1 * 8 + j];
    float f4 = g[(3 * 8 + i) * 32 + 2 * 8 + j];
    float f5 = g[(2 * 8 + i) * 32 + 3 * 8 + j];
    float f6 = g[(3 * 8 + i) * 32 + 3 * 8 + j];

    float acc = bias[n];
    acc += f0 * W[0 * 256 + n];
    acc += f1 * W[1 * 256 + n];
    acc += f2 * W[2 * 256 + n];
    acc += f3 * W[3 * 256 + n];
    acc += f4 * W[4 * 256 + n];
    acc += f5 * W[5 * 256 + n];
    acc += f6 * W[6 * 256 + n];
    out[((size_t)b * 64 + p) * 256 + n] = acc;
}

extern "C" void kernel_launch(void* const* d_in, const int* in_sizes, int n_in,
                              void* d_out, int out_size, void* d_ws, size_t ws_size,
                              hipStream_t stream) {
    (void)in_sizes; (void)n_in; (void)out_size; (void)ws_size;
    const float* x    = (const float*)d_in[0];
    const float* W    = (const float*)d_in[1];
    const float* bias = (const float*)d_in[2];
    float* ws = (float*)d_ws;
    float* Fc = ws + 6144;
    float* T2 = ws + 38912;
    float* G  = ws + 2136064;
    float* out = (float*)d_out;

    hipLaunchKernelGGL(init_weights, dim3(1), dim3(256), 0, stream, ws);
    hipLaunchKernelGGL(k1_rowreduce, dim3(16, 64), dim3(256), 0, stream, x, ws, T2);
    hipLaunchKernelGGL(k2_colreduce, dim3(64), dim3(256), 0, stream, T2, Fc, G);
    hipLaunchKernelGGL(k3_project, dim3(64, 64), dim3(256), 0, stream, G, W, bias, out);
}

// Round 3
// 446.262 us; speedup vs baseline: 1.2584x; 1.2584x over previous
//
#include <hip/hip_runtime.h>
#include <math.h>

#define IS2 0.70710678118654752440f

// d_ws layout (float elements):
//   K2  [512][8]            @ 0        (is2 * K512[i][m2], transposed)
//   K4  [256][8]            @ 4096     (0.5 * K256[i][m4], transposed)
//   Fc  [32][1024]          @ 6144     (dense column functionals)
//   T2  [64][32][1024]      @ 38912    (row-reduced per image)
//   P   [64][16][32][32]    @ 2136064  (per-q-chunk partial G)
// total = 3,184,640 floats = 12.7 MB

__device__ __forceinline__ float tri_f(float x) {
    float a = 1.0f - fabsf(x);
    return a > 0.0f ? a : 0.0f;
}

__global__ void init_weights(float* __restrict__ ws) {
    __shared__ float norm512[8];
    __shared__ float norm256[8];
    int t = threadIdx.x;
    if (t < 8) {
        float c = 64.0f * t + 31.5f;
        float s = 0.0f;
        for (int m = 0; m < 512; ++m) s += tri_f((m - c) * (1.0f / 64.0f));
        norm512[t] = s;
    } else if (t < 16) {
        int i = t - 8;
        float c = 32.0f * i + 15.5f;
        float s = 0.0f;
        for (int m = 0; m < 256; ++m) s += tri_f((m - c) * (1.0f / 32.0f));
        norm256[i] = s;
    }
    __syncthreads();

    float* K2 = ws;
    float* K4 = ws + 4096;
    float* Fc = ws + 6144;

    for (int idx = t; idx < 4096; idx += 256) {
        int m2 = idx >> 3, i = idx & 7;
        K2[idx] = IS2 * tri_f((m2 - (64.0f * i + 31.5f)) * (1.0f / 64.0f)) / norm512[i];
    }
    for (int idx = t; idx < 2048; idx += 256) {
        int m4 = idx >> 3, i = idx & 7;
        K4[idx] = 0.5f * tri_f((m4 - (32.0f * i + 15.5f)) * (1.0f / 32.0f)) / norm256[i];
    }
    for (int idx = t; idx < 32768; idx += 256) {
        int jp = idx >> 10, q = idx & 1023;
        int s = jp >> 3, i = jp & 7;
        float v;
        if (s == 0) {
            v = 0.5f * tri_f(((q >> 2) - (32.0f * i + 15.5f)) * (1.0f / 32.0f)) / norm256[i];
        } else if (s == 1) {
            float sg = ((q & 3) < 2) ? 1.0f : -1.0f;
            v = sg * 0.5f * tri_f(((q >> 2) - (32.0f * i + 15.5f)) * (1.0f / 32.0f)) / norm256[i];
        } else if (s == 2) {
            v = IS2 * tri_f(((q >> 1) - (64.0f * i + 31.5f)) * (1.0f / 64.0f)) / norm512[i];
        } else {
            float sg = ((q & 1) == 0) ? 1.0f : -1.0f;
            v = sg * IS2 * tri_f(((q >> 1) - (64.0f * i + 31.5f)) * (1.0f / 64.0f)) / norm512[i];
        }
        Fc[idx] = v;
    }
}

// k1: row-direction reduction. Grid (16 col-chunks, 64 images), block 256 = 4 waves.
// Wave w handles rows [w*256, (w+1)*256), column q = chunk*64 + lane.
__global__ __launch_bounds__(256) void k1_rowreduce(const float* __restrict__ x,
                                                    const float* __restrict__ ws,
                                                    float* __restrict__ T2) {
    const int b = blockIdx.y;
    const int chunk = blockIdx.x;
    const int t = threadIdx.x;
    const int w = t >> 6;
    const int l = t & 63;
    const int q = chunk * 64 + l;

    const float* K2 = ws;
    const float* K4 = ws + 4096;
    const float* xp = x + (size_t)b * 1048576 + (size_t)(w * 256) * 1024 + q;

    float acc0[8], acc1[8], acc2[8], acc3[8];
#pragma unroll
    for (int i = 0; i < 8; ++i) { acc0[i] = 0.f; acc1[i] = 0.f; acc2[i] = 0.f; acc3[i] = 0.f; }

    const int m2base = w * 128;
    const int m4base = w * 64;

    for (int g = 0; g < 64; ++g) {
        float x0 = xp[0];
        float x1 = xp[1024];
        float x2 = xp[2048];
        float x3 = xp[3072];
        xp += 4096;
        float a2a = x0 + x1, d2a = x0 - x1;
        float a2b = x2 + x3, d2b = x2 - x3;
        float s4 = a2a + a2b, r4 = a2a - a2b;
        const float* wa = K2 + (size_t)(m2base + 2 * g) * 8;
        const float* wb = wa + 8;
        const float* w4 = K4 + (size_t)(m4base + g) * 8;
#pragma unroll
        for (int i = 0; i < 8; ++i) {
            float wai = wa[i], wbi = wb[i], w4i = w4[i];
            acc2[i] += wai * a2a + wbi * a2b;
            acc3[i] += wai * d2a + wbi * d2b;
            acc0[i] += w4i * s4;
            acc1[i] += w4i * r4;
        }
    }

    __shared__ float red[4][32][64];
#pragma unroll
    for (int i = 0; i < 8; ++i) {
        red[w][i][l]      = acc0[i];
        red[w][8 + i][l]  = acc1[i];
        red[w][16 + i][l] = acc2[i];
        red[w][24 + i][l] = acc3[i];
    }
    __syncthreads();

    for (int idx = t; idx < 2048; idx += 256) {
        int jp = idx >> 6, c = idx & 63;
        float s = red[0][jp][c] + red[1][jp][c] + red[2][jp][c] + red[3][jp][c];
        T2[((size_t)b * 32 + jp) * 1024 + chunk * 64 + c] = s;
    }
}

// k2: partial G over a 64-column chunk. Grid (16 chunks, 64 images), block 256.
// P[b][ch][jp][jpp] = sum_{c in chunk} T2[b][jp][c] * Fc[jpp][c]
__global__ __launch_bounds__(256) void k2_colreduce(const float* __restrict__ T2,
                                                    const float* __restrict__ Fc,
                                                    float* __restrict__ P) {
    const int b = blockIdx.y;
    const int ch = blockIdx.x;
    const int t = threadIdx.x;

    __shared__ float Tl[32][64];
    __shared__ float Fl[32][65];   // pad 65: bank = (jpp + c) % 32 -> conflict-free

    for (int idx = t; idx < 2048; idx += 256) {
        int r = idx >> 6, c = idx & 63;
        Tl[r][c] = T2[((size_t)b * 32 + r) * 1024 + ch * 64 + c];
        Fl[r][c] = Fc[(size_t)r * 1024 + ch * 64 + c];
    }
    __syncthreads();

    const int jpp = t & 31;
    const int jp0 = t >> 5;   // 0..7
    float s0 = 0.f, s1 = 0.f, s2 = 0.f, s3 = 0.f;
#pragma unroll 4
    for (int c = 0; c < 64; ++c) {
        float f = Fl[jpp][c];
        s0 += Tl[jp0][c] * f;
        s1 += Tl[jp0 + 8][c] * f;
        s2 += Tl[jp0 + 16][c] * f;
        s3 += Tl[jp0 + 24][c] * f;
    }
    float* p = P + (((size_t)b * 16 + ch) * 32) * 32 + jpp;
    p[(jp0)      * 32] = s0;
    p[(jp0 + 8)  * 32] = s1;
    p[(jp0 + 16) * 32] = s2;
    p[(jp0 + 24) * 32] = s3;
}

// k3: out[b, p, n] = bias[n] + sum_k feat_k * W[k][n], feat from 16-chunk partial sums.
__global__ __launch_bounds__(256) void k3_project(const float* __restrict__ P,
                                                  const float* __restrict__ W,
                                                  const float* __restrict__ bias,
                                                  float* __restrict__ out) {
    const int b = blockIdx.y;
    const int p = blockIdx.x;
    const int n = threadIdx.x;
    const int i = p >> 3, j = p & 7;
    // maps: cA2(0,0) cH2(1,0) cV2(0,1) cD2(1,1) cH1(3,2) cV1(2,3) cD1(3,3)
    const int rs[7] = {0, 1, 0, 1, 3, 2, 3};
    const int cs[7] = {0, 0, 1, 1, 2, 3, 3};

    float acc = bias[n];
#pragma unroll
    for (int s = 0; s < 7; ++s) {
        const float* pp = P + ((size_t)b * 16 * 32 + rs[s] * 8 + i) * 32 + cs[s] * 8 + j;
        float f = 0.f;
#pragma unroll
        for (int ch = 0; ch < 16; ++ch) f += pp[(size_t)ch * 1024];
        acc += f * W[s * 256 + n];
    }
    out[((size_t)b * 64 + p) * 256 + n] = acc;
}

extern "C" void kernel_launch(void* const* d_in, const int* in_sizes, int n_in,
                              void* d_out, int out_size, void* d_ws, size_t ws_size,
                              hipStream_t stream) {
    (void)in_sizes; (void)n_in; (void)out_size; (void)ws_size;
    const float* x    = (const float*)d_in[0];
    const float* W    = (const float*)d_in[1];
    const float* bias = (const float*)d_in[2];
    float* ws = (float*)d_ws;
    float* Fc = ws + 6144;
    float* T2 = ws + 38912;
    float* P  = ws + 2136064;
    float* out = (float*)d_out;

    hipLaunchKernelGGL(init_weights, dim3(1), dim3(256), 0, stream, ws);
    hipLaunchKernelGGL(k1_rowreduce, dim3(16, 64), dim3(256), 0, stream, x, ws, T2);
    hipLaunchKernelGGL(k2_colreduce, dim3(16, 64), dim3(256), 0, stream, T2, Fc, P);
    hipLaunchKernelGGL(k3_project, dim3(64, 64), dim3(256), 0, stream, P, W, bias, out);
}

// Round 4
// 412.806 us; speedup vs baseline: 1.3604x; 1.0810x over previous
//
#include <hip/hip_runtime.h>
#include <math.h>

#define IS2 0.70710678118654752440f

// d_ws layout (float elements):
//   K2  [512][8]            @ 0        (is2 * K512[i][m2], transposed)
//   K4  [256][8]            @ 4096     (0.5 * K256[i][m4], transposed)
//   Fc  [32][1024]          @ 6144     (dense column functionals)
//   P   [64][16][32][32]    @ 2136064  (per-q-chunk partial G; offset kept from r3)

__device__ __forceinline__ float tri_f(float x) {
    float a = 1.0f - fabsf(x);
    return a > 0.0f ? a : 0.0f;
}

// Analytic truncated-triangle norms (partition of unity: interior = scale;
// edges lose exactly 8 of 64 / 4 of 32 — derived in closed form, exact in fp32).
__device__ __forceinline__ float n512f(int i) { return (i == 0 || i == 7) ? 56.0f : 64.0f; }
__device__ __forceinline__ float n256f(int i) { return (i == 0 || i == 7) ? 28.0f : 32.0f; }

// Fills K2[4096], K4[2048], Fc[32768]. Grid 152 x 256.
__global__ __launch_bounds__(256) void init_weights(float* __restrict__ ws) {
    int idx = blockIdx.x * 256 + threadIdx.x;
    if (idx >= 38912) return;
    if (idx < 4096) {
        int m2 = idx >> 3, i = idx & 7;
        ws[idx] = IS2 * tri_f((m2 - (64.0f * i + 31.5f)) * (1.0f / 64.0f)) / n512f(i);
    } else if (idx < 6144) {
        int j = idx - 4096;
        int m4 = j >> 3, i = j & 7;
        ws[idx] = 0.5f * tri_f((m4 - (32.0f * i + 15.5f)) * (1.0f / 32.0f)) / n256f(i);
    } else {
        int j = idx - 6144;
        int jp = j >> 10, q = j & 1023;
        int s = jp >> 3, i = jp & 7;
        float v;
        if (s == 0) {
            v = 0.5f * tri_f(((q >> 2) - (32.0f * i + 15.5f)) * (1.0f / 32.0f)) / n256f(i);
        } else if (s == 1) {
            float sg = ((q & 3) < 2) ? 1.0f : -1.0f;
            v = sg * 0.5f * tri_f(((q >> 2) - (32.0f * i + 15.5f)) * (1.0f / 32.0f)) / n256f(i);
        } else if (s == 2) {
            v = IS2 * tri_f(((q >> 1) - (64.0f * i + 31.5f)) * (1.0f / 64.0f)) / n512f(i);
        } else {
            float sg = ((q & 1) == 0) ? 1.0f : -1.0f;
            v = sg * IS2 * tri_f(((q >> 1) - (64.0f * i + 31.5f)) * (1.0f / 64.0f)) / n512f(i);
        }
        ws[idx] = v;
    }
}

// k1_fused: row reduction + in-block column contraction -> P directly (k2 fused away).
// Grid (16 col-chunks, 64 images), block 256 = 4 waves.
// Wave w handles rows [w*256, (w+1)*256), column q = chunk*64 + lane.
// LDS: red[4][32][64] (32 KiB) + Fl[2048] swizzled (8 KiB) = 40 KiB -> 4 blocks/CU.
__global__ __launch_bounds__(256) void k1_fused(const float* __restrict__ x,
                                                const float* __restrict__ ws,
                                                float* __restrict__ P) {
    const int b = blockIdx.y;
    const int chunk = blockIdx.x;
    const int t = threadIdx.x;
    const int w = t >> 6;
    const int l = t & 63;
    const int q = chunk * 64 + l;

    __shared__ float red[4][32][64];
    __shared__ float Fl[2048];   // Fc chunk, stored at [r][(c+r)&63] -> conflict-free reads

    // Stage Fc chunk (8 KB) into LDS; overlaps with main-loop global traffic.
    for (int idx = t; idx < 2048; idx += 256) {
        int r = idx >> 6, c = idx & 63;
        Fl[r * 64 + ((c + r) & 63)] = ws[6144 + (size_t)r * 1024 + chunk * 64 + c];
    }

    const float* K2 = ws;
    const float* K4 = ws + 4096;
    const float* xp = x + (size_t)b * 1048576 + (size_t)(w * 256) * 1024 + q;

    float acc0[8], acc1[8], acc2[8], acc3[8];
#pragma unroll
    for (int i = 0; i < 8; ++i) { acc0[i] = 0.f; acc1[i] = 0.f; acc2[i] = 0.f; acc3[i] = 0.f; }

    const int m2base = w * 128;
    const int m4base = w * 64;

    for (int g = 0; g < 64; ++g) {
        float x0 = xp[0];
        float x1 = xp[1024];
        float x2 = xp[2048];
        float x3 = xp[3072];
        xp += 4096;
        float a2a = x0 + x1, d2a = x0 - x1;
        float a2b = x2 + x3, d2b = x2 - x3;
        float s4 = a2a + a2b, r4 = a2a - a2b;
        const float* wa = K2 + (size_t)(m2base + 2 * g) * 8;
        const float* wb = wa + 8;
        const float* w4 = K4 + (size_t)(m4base + g) * 8;
#pragma unroll
        for (int i = 0; i < 8; ++i) {
            float wai = wa[i], wbi = wb[i], w4i = w4[i];
            acc2[i] += wai * a2a + wbi * a2b;
            acc3[i] += wai * d2a + wbi * d2b;
            acc0[i] += w4i * s4;
            acc1[i] += w4i * r4;
        }
    }

#pragma unroll
    for (int i = 0; i < 8; ++i) {
        red[w][i][l]      = acc0[i];
        red[w][8 + i][l]  = acc1[i];
        red[w][16 + i][l] = acc2[i];
        red[w][24 + i][l] = acc3[i];
    }
    __syncthreads();

    // Sum the 4 wave-partials in place into red[0] (one writer per entry).
    for (int idx = t; idx < 2048; idx += 256) {
        int jp = idx >> 6, c = idx & 63;
        red[0][jp][c] = red[0][jp][c] + red[1][jp][c] + red[2][jp][c] + red[3][jp][c];
    }
    __syncthreads();

    // P[b][ch][jp][jpp] = sum_c Tsum[jp][c] * Fc[jpp][ch*64+c]
    const int jpp = t & 31;
    const int jp0 = t >> 5;   // 0..7
    float s0 = 0.f, s1 = 0.f, s2 = 0.f, s3 = 0.f;
#pragma unroll 4
    for (int c = 0; c < 64; ++c) {
        float f = Fl[jpp * 64 + ((c + jpp) & 63)];
        s0 += red[0][jp0][c]      * f;
        s1 += red[0][jp0 + 8][c]  * f;
        s2 += red[0][jp0 + 16][c] * f;
        s3 += red[0][jp0 + 24][c] * f;
    }
    float* p = P + (((size_t)b * 16 + chunk) * 32) * 32 + jpp;
    p[(jp0)      * 32] = s0;
    p[(jp0 + 8)  * 32] = s1;
    p[(jp0 + 16) * 32] = s2;
    p[(jp0 + 24) * 32] = s3;
}

// k3: out[b, p, n] = bias[n] + sum_k feat_k * W[k][n], feat from 16-chunk partial sums.
__global__ __launch_bounds__(256) void k3_project(const float* __restrict__ P,
                                                  const float* __restrict__ W,
                                                  const float* __restrict__ bias,
                                                  float* __restrict__ out) {
    const int b = blockIdx.y;
    const int p = blockIdx.x;
    const int n = threadIdx.x;
    const int i = p >> 3, j = p & 7;
    // maps: cA2(0,0) cH2(1,0) cV2(0,1) cD2(1,1) cH1(3,2) cV1(2,3) cD1(3,3)
    const int rs[7] = {0, 1, 0, 1, 3, 2, 3};
    const int cs[7] = {0, 0, 1, 1, 2, 3, 3};

    float acc = bias[n];
#pragma unroll
    for (int s = 0; s < 7; ++s) {
        const float* pp = P + ((size_t)b * 16 * 32 + rs[s] * 8 + i) * 32 + cs[s] * 8 + j;
        float f = 0.f;
#pragma unroll
        for (int ch = 0; ch < 16; ++ch) f += pp[(size_t)ch * 1024];
        acc += f * W[s * 256 + n];
    }
    out[((size_t)b * 64 + p) * 256 + n] = acc;
}

extern "C" void kernel_launch(void* const* d_in, const int* in_sizes, int n_in,
                              void* d_out, int out_size, void* d_ws, size_t ws_size,
                              hipStream_t stream) {
    (void)in_sizes; (void)n_in; (void)out_size; (void)ws_size;
    const float* x    = (const float*)d_in[0];
    const float* W    = (const float*)d_in[1];
    const float* bias = (const float*)d_in[2];
    float* ws = (float*)d_ws;
    float* P  = ws + 2136064;
    float* out = (float*)d_out;

    hipLaunchKernelGGL(init_weights, dim3(152), dim3(256), 0, stream, ws);
    hipLaunchKernelGGL(k1_fused, dim3(16, 64), dim3(256), 0, stream, x, ws, P);
    hipLaunchKernelGGL(k3_project, dim3(64, 64), dim3(256), 0, stream, P, W, bias, out);
}